// Round 12
// baseline (406.636 us; speedup 1.0000x reference)
//
#include <hip/hip_runtime.h>

#define DIM 128
#define BN_EPS 1e-5f

// ---- bf16 helpers ----
__device__ __forceinline__ float bflo(unsigned int h) {
    return __uint_as_float(h << 16);
}
__device__ __forceinline__ float bfhi(unsigned int h) {
    return __uint_as_float(h & 0xffff0000u);
}
__device__ __forceinline__ unsigned int f2bf(float f) {
    unsigned int u = __float_as_uint(f);
    return (u + 0x7fffu + ((u >> 16) & 1u)) >> 16;   // round-to-nearest-even
}
__device__ __forceinline__ unsigned int pack2(float a, float b) {
    return f2bf(a) | (f2bf(b) << 16);
}

// ---------------------------------------------------------------------------
// init: zero degree counters and BN stats accumulators
__global__ __launch_bounds__(256) void k_init(int* __restrict__ deg_cnt,
                                              float* __restrict__ stats, int n) {
    int i = blockIdx.x * 256 + threadIdx.x;
    if (i < n) deg_cnt[i] = 0;
    if (i < 512) stats[i] = 0.0f;
}

// in-degree histogram over dst
__global__ __launch_bounds__(256) void k_deg(const int* __restrict__ dst,
                                             int* __restrict__ deg_cnt, int e) {
    int i = blockIdx.x * 256 + threadIdx.x;
    if (i < e) atomicAdd(&deg_cnt[dst[i]], 1);
}

// dinv[i] = rsqrt(deg_cnt[i] + 1)   (self-loop adds 1)
__global__ __launch_bounds__(256) void k_dinv(const int* __restrict__ deg_cnt,
                                              float* __restrict__ dinv, int n) {
    int i = blockIdx.x * 256 + threadIdx.x;
    if (i < n) dinv[i] = rsqrtf((float)deg_cnt[i] + 1.0f);
}

// ---------------------------------------------------------------------------
// hierarchical exclusive scan (all 256-thread blocks)
__device__ __forceinline__ int wave_scan_incl(int v) {
    int lane = threadIdx.x & 63;
#pragma unroll
    for (int off = 1; off < 64; off <<= 1) {
        int t = __shfl_up(v, off, 64);
        if (lane >= off) v += t;
    }
    return v;
}

__global__ __launch_bounds__(256) void k_scan1(const int* __restrict__ deg_cnt,
                                               int* __restrict__ row_start,
                                               int* __restrict__ blk_sum, int n) {
    int tid = threadIdx.x;
    int i = blockIdx.x * 256 + tid;
    int v = (i < n) ? deg_cnt[i] : 0;
    int inc = wave_scan_incl(v);
    __shared__ int wtot[4];
    int wave = tid >> 6, lane = tid & 63;
    if (lane == 63) wtot[wave] = inc;
    __syncthreads();
    int woff = 0;
    for (int w = 0; w < wave; ++w) woff += wtot[w];
    int excl = woff + inc - v;
    if (i < n) row_start[i] = excl;
    if (tid == 255) blk_sum[blockIdx.x] = woff + inc;
}

__global__ __launch_bounds__(256) void k_scan2(const int* __restrict__ blk_sum,
                                               int* __restrict__ blk_off,
                                               int* __restrict__ row_start,
                                               int nblk, int n) {
    int tid = threadIdx.x;
    int v = (tid < nblk) ? blk_sum[tid] : 0;
    int inc = wave_scan_incl(v);
    __shared__ int wtot[4];
    int wave = tid >> 6, lane = tid & 63;
    if (lane == 63) wtot[wave] = inc;
    __syncthreads();
    int woff = 0;
    for (int w = 0; w < wave; ++w) woff += wtot[w];
    if (tid < nblk) blk_off[tid] = woff + inc - v;
    if (tid == 255) row_start[n] = woff + inc;   // grand total
}

__global__ __launch_bounds__(256) void k_scan3(int* __restrict__ row_start,
                                               const int* __restrict__ blk_off,
                                               int* __restrict__ cursor, int n) {
    int i = blockIdx.x * 256 + threadIdx.x;
    if (i < n) {
        int rs = row_start[i] + blk_off[blockIdx.x];
        row_start[i] = rs;
        cursor[i] = rs;
    }
}

// ---------------------------------------------------------------------------
// K-chunked GEMM body: H[r0b..r0b+31, :] = X[r0b..,:] @ W, bf16 output.
// Stages W in 16-row chunks (8 KB) + 32x16 X slice (2 KB) -> 10 KB LDS, so
// the fused kernel's fill blocks are not LDS-occupancy-capped.
__device__ __forceinline__ void gemm_tile(const float* __restrict__ X,
                                          const float* __restrict__ W,
                                          unsigned short* __restrict__ H,
                                          int n, int r0b,
                                          float* __restrict__ ws,   // [16*DIM]
                                          float* __restrict__ xs) { // [32*16]
    int t = threadIdx.x;
    int ty = t >> 5;          // 0..7 -> 4-row group
    int tx = t & 31;          // 0..31 -> 4-col group
    int r0 = ty * 4;
    int c0 = tx * 4;
    float acc[4][4] = {};

    const float4* W4 = (const float4*)W;
    const float4* X4 = (const float4*)X;
    float4* ws4 = (float4*)ws;
    float4* xs4 = (float4*)xs;

    for (int c = 0; c < 8; ++c) {          // 8 chunks of K=16
        int k0 = c * 16;
        if (c) __syncthreads();            // protect LDS reuse
        // stage W rows k0..k0+15 (full 128 cols): 512 float4
#pragma unroll
        for (int i = 0; i < 2; ++i) {
            int idx = t + 256 * i;         // 0..511
            ws4[idx] = W4[k0 * 32 + idx];
        }
        // stage X rows r0b..r0b+31, cols k0..k0+15: 128 float4
        if (t < 128) {
            int row = t >> 2;              // 0..31
            int cg  = t & 3;               // float4 within 16-col slice
            float4 v = make_float4(0.f, 0.f, 0.f, 0.f);
            if (r0b + row < n) v = X4[(size_t)(r0b + row) * 32 + (k0 >> 2) + cg];
            xs4[t] = v;
        }
        __syncthreads();
#pragma unroll
        for (int k = 0; k < 16; ++k) {
            float4 b = *(const float4*)&ws[k * DIM + c0];
            float a0 = xs[(r0 + 0) * 16 + k];
            float a1 = xs[(r0 + 1) * 16 + k];
            float a2 = xs[(r0 + 2) * 16 + k];
            float a3 = xs[(r0 + 3) * 16 + k];
            acc[0][0] += a0 * b.x; acc[0][1] += a0 * b.y; acc[0][2] += a0 * b.z; acc[0][3] += a0 * b.w;
            acc[1][0] += a1 * b.x; acc[1][1] += a1 * b.y; acc[1][2] += a1 * b.z; acc[1][3] += a1 * b.w;
            acc[2][0] += a2 * b.x; acc[2][1] += a2 * b.y; acc[2][2] += a2 * b.z; acc[2][3] += a2 * b.w;
            acc[3][0] += a3 * b.x; acc[3][1] += a3 * b.y; acc[3][2] += a3 * b.z; acc[3][3] += a3 * b.w;
        }
    }
#pragma unroll
    for (int i = 0; i < 4; ++i) {
        int row = r0b + r0 + i;
        if (row < n) {
            uint2 pv;
            pv.x = pack2(acc[i][0], acc[i][1]);
            pv.y = pack2(acc[i][2], acc[i][3]);
            *(uint2*)&H[(size_t)row * DIM + c0] = pv;   // 8B-aligned
        }
    }
}

// ---------------------------------------------------------------------------
// FUSED: blocks [0,fillBlocks) build the CSR edge array (memory-latency-bound
// scatter); blocks [fillBlocks, ...) compute H = X @ W1. 10 KB LDS keeps the
// fill path occupancy-uncapped; branch is block-uniform.
__global__ __launch_bounds__(256) void k_fill_gemm(
        const int* __restrict__ src, const int* __restrict__ dst,
        const float* __restrict__ dinv, int* __restrict__ cursor,
        int2* __restrict__ edge, int e, int fillBlocks,
        const float* __restrict__ X, const float* __restrict__ W,
        unsigned short* __restrict__ H, int n) {
    __shared__ float ws[16 * DIM];   // 8 KB
    __shared__ float xs[32 * 16];    // 2 KB

    if ((int)blockIdx.x < fillBlocks) {
        int i = blockIdx.x * 256 + threadIdx.x;
        if (i < e) {
            int s = src[i], t = dst[i];
            int pos = atomicAdd(&cursor[t], 1);
            float w = dinv[s] * dinv[t];
            edge[pos] = make_int2(s, __float_as_int(w));
        }
        return;
    }
    gemm_tile(X, W, H, n, ((int)blockIdx.x - fillBlocks) * 32, ws, xs);
}

// H = X @ W   (standalone, used for conv2)
__global__ __launch_bounds__(256) void k_gemm(const float* __restrict__ X,
                                              const float* __restrict__ W,
                                              unsigned short* __restrict__ H, int n) {
    __shared__ float ws[16 * DIM];   // 8 KB
    __shared__ float xs[32 * 16];    // 2 KB
    gemm_tile(X, W, H, n, blockIdx.x * 32, ws, xs);
}

// ---------------------------------------------------------------------------
// out[i,:] = sum_{j in in-edges(i)} H[edge[j].x,:]*edge[j].w + H[i,:]*dinv[i]^2 + bias
// H is bf16. ONE WAVE per node (4 nodes / 256-thr block); lane owns channels
// 2*lane, 2*lane+1 via one packed uint load per edge; 8-edge unroll.
__global__ __launch_bounds__(256) void k_agg(const unsigned int* __restrict__ Hp,  // bf16 pairs
                                             const float* __restrict__ bias,
                                             const float* __restrict__ dinv,
                                             const int* __restrict__ row_start,
                                             const int2* __restrict__ edge,
                                             float* __restrict__ out, int n, int e) {
    int node = blockIdx.x * 4 + (threadIdx.x >> 6);
    int lane = threadIdx.x & 63;
    if (node >= n) return;
    float di = dinv[node];
    float dsq = di * di;
    float b0 = bias[2 * lane];
    float b1 = bias[2 * lane + 1];
    unsigned int hs = Hp[(size_t)node * 64 + lane];
    float a0 = bflo(hs) * dsq + b0;
    float a1 = bfhi(hs) * dsq + b1;
    int jb = row_start[node], je = row_start[node + 1];
    jb = min(max(jb, 0), e);          // clamp: garbage can't cause hang/OOB
    je = min(max(je, jb), e);
    int j = jb;
    for (; j + 8 <= je; j += 8) {
        int2 ed[8]; unsigned int h[8];
#pragma unroll
        for (int u = 0; u < 8; ++u) ed[u] = edge[j + u];
#pragma unroll
        for (int u = 0; u < 8; ++u) h[u] = Hp[(size_t)ed[u].x * 64 + lane];
#pragma unroll
        for (int u = 0; u < 8; ++u) {
            float w = __int_as_float(ed[u].y);
            a0 += bflo(h[u]) * w;
            a1 += bfhi(h[u]) * w;
        }
    }
    for (; j < je; ++j) {
        int2 ed = edge[j];
        float w = __int_as_float(ed.y);
        unsigned int h = Hp[(size_t)ed.x * 64 + lane];
        a0 += bflo(h) * w;
        a1 += bfhi(h) * w;
    }
    out[(size_t)node * DIM + 2 * lane]     = a0;
    out[(size_t)node * DIM + 2 * lane + 1] = a1;
}

// ---------------------------------------------------------------------------
// column sums + sums of squares -> sums[0..127]=sum, sums[128..255]=sumsq
__global__ __launch_bounds__(256) void k_stats(const float* __restrict__ V,
                                               float* __restrict__ sums, int n) {
    int d = threadIdx.x & 127;
    int half = threadIdx.x >> 7;
    int r0 = blockIdx.x * 256;
    int r1 = min(r0 + 256, n);
    float s = 0.f, q = 0.f;
    for (int r = r0 + half; r < r1; r += 2) {
        float v = V[(size_t)r * DIM + d];
        s += v; q += v * v;
    }
    __shared__ float ls[256], lq[256];
    ls[threadIdx.x] = s; lq[threadIdx.x] = q;
    __syncthreads();
    if (half == 0) {
        atomicAdd(&sums[d], s + ls[threadIdx.x + 128]);
        atomicAdd(&sums[128 + d], q + lq[threadIdx.x + 128]);
    }
}

// BN (training-mode batch stats) + ReLU, in place
__global__ __launch_bounds__(256) void k_bn_relu(float* __restrict__ V,
                                                 const float* __restrict__ sums,
                                                 const float* __restrict__ gamma,
                                                 const float* __restrict__ beta,
                                                 int n, float invN) {
    int idx = blockIdx.x * 256 + threadIdx.x;
    if (idx >= n * DIM) return;
    int d = idx & 127;
    float mu = sums[d] * invN;
    float var = sums[128 + d] * invN - mu * mu;
    float inv = rsqrtf(var + BN_EPS);
    float scale = gamma[d] * inv;
    float shift = beta[d] - mu * scale;
    float v = V[idx] * scale + shift;
    V[idx] = fmaxf(v, 0.f);
}

// BN + residual + ReLU -> out (element-wise; safe when V == out)
__global__ __launch_bounds__(256) void k_bn_res_relu(const float* __restrict__ V,
                                                     const float* __restrict__ X,
                                                     const float* __restrict__ sums,
                                                     const float* __restrict__ gamma,
                                                     const float* __restrict__ beta,
                                                     float* __restrict__ out,
                                                     int n, float invN) {
    int idx = blockIdx.x * 256 + threadIdx.x;
    if (idx >= n * DIM) return;
    int d = idx & 127;
    float mu = sums[d] * invN;
    float var = sums[128 + d] * invN - mu * mu;
    float inv = rsqrtf(var + BN_EPS);
    float scale = gamma[d] * inv;
    float shift = beta[d] - mu * scale;
    float v = V[idx] * scale + shift + X[idx];
    out[idx] = fmaxf(v, 0.f);
}

// ---------------------------------------------------------------------------
extern "C" void kernel_launch(void* const* d_in, const int* in_sizes, int n_in,
                              void* d_out, int out_size, void* d_ws, size_t ws_size,
                              hipStream_t stream) {
    const float* x      = (const float*)d_in[0];
    const int*   ei     = (const int*)d_in[1];
    const float* W1     = (const float*)d_in[2];
    const float* b1     = (const float*)d_in[3];
    const float* gamma1 = (const float*)d_in[4];
    const float* beta1  = (const float*)d_in[5];
    const float* W2     = (const float*)d_in[6];
    const float* b2     = (const float*)d_in[7];
    const float* gamma2 = (const float*)d_in[8];
    const float* beta2  = (const float*)d_in[9];
    float* out = (float*)d_out;

    int n = in_sizes[0] / DIM;   // 50000
    int e = in_sizes[1] / 2;     // 800000
    const int* srcIdx = ei;       // edge_index[0,:]
    const int* dstIdx = ei + e;   // edge_index[1,:]

    int gN    = (n + 255) / 256;
    int gE    = (e + 255) / 256;
    int gRows = (n + 31) / 32;
    int gNode = (n + 3) / 4;
    int gElem = (n * DIM + 255) / 256;
    float invN = 1.0f / (float)n;

    char* ws = (char*)d_ws;
    size_t off = 0;
    auto alloc = [&](size_t bytes) -> void* {
        void* p = ws + off;
        off += (bytes + 255) & ~(size_t)255;
        return p;
    };
    int*   deg_cnt   = (int*)  alloc((size_t)n * 4);
    float* dinv      = (float*)alloc((size_t)n * 4);
    int*   row_start = (int*)  alloc((size_t)(n + 1) * 4);
    int*   cursor    = (int*)  alloc((size_t)n * 4);
    int*   blk_sum   = (int*)  alloc((size_t)gN * 4);
    int*   blk_off   = (int*)  alloc((size_t)gN * 4);
    int2*  edge      = (int2*) alloc((size_t)e * 8);              // (src, wgt)
    unsigned short* Hb = (unsigned short*)alloc((size_t)n * DIM * 2);  // bf16 H
    float* stats     = (float*)alloc(512 * 4);   // [stats1 | stats2]
    float* stats1 = stats;
    float* stats2 = stats + 256;
    // d_out doubles as the fp32 N x D buffer (fully overwritten at the end,
    // final BN pass is element-wise in-place-safe).
    float* bufB = out;

    // workspace guard: fail cleanly (wrong output) instead of corrupting memory
    if (off > ws_size || gN > 256) return;

    // graph preprocessing: degrees -> dinv -> CSR prefix
    k_init<<<gN, 256, 0, stream>>>(deg_cnt, stats, n);
    k_deg<<<gE, 256, 0, stream>>>(dstIdx, deg_cnt, e);
    k_dinv<<<gN, 256, 0, stream>>>(deg_cnt, dinv, n);
    k_scan1<<<gN, 256, 0, stream>>>(deg_cnt, row_start, blk_sum, n);
    k_scan2<<<1, 256, 0, stream>>>(blk_sum, blk_off, row_start, gN, n);
    k_scan3<<<gN, 256, 0, stream>>>(row_start, blk_off, cursor, n);

    // FUSED: CSR fill (latency-bound) || GEMM1 (VALU-bound) — independent work
    k_fill_gemm<<<gE + gRows, 256, 0, stream>>>(
        srcIdx, dstIdx, dinv, cursor, edge, e, gE,
        x, W1, Hb, n);

    // conv1 aggregation + BN + ReLU
    k_agg<<<gNode, 256, 0, stream>>>((const unsigned int*)Hb, b1, dinv, row_start, edge, bufB, n, e);
    k_stats<<<gN, 256, 0, stream>>>(bufB, stats1, n);
    k_bn_relu<<<gElem, 256, 0, stream>>>(bufB, stats1, gamma1, beta1, n, invN);

    // conv2 + BN + residual + ReLU
    k_gemm<<<gRows, 256, 0, stream>>>(bufB, W2, Hb, n);
    k_agg<<<gNode, 256, 0, stream>>>((const unsigned int*)Hb, b2, dinv, row_start, edge, bufB, n, e);
    k_stats<<<gN, 256, 0, stream>>>(bufB, stats2, n);
    k_bn_res_relu<<<gElem, 256, 0, stream>>>(bufB, x, stats2, gamma2, beta2, out, n, invN);
}

// Round 13
// 400.248 us; speedup vs baseline: 1.0160x; 1.0160x over previous
//
#include <hip/hip_runtime.h>

#define DIM 128
#define BN_EPS 1e-5f

// ---- bf16 helpers ----
__device__ __forceinline__ float bflo(unsigned int h) {
    return __uint_as_float(h << 16);
}
__device__ __forceinline__ float bfhi(unsigned int h) {
    return __uint_as_float(h & 0xffff0000u);
}
__device__ __forceinline__ unsigned int f2bf(float f) {
    unsigned int u = __float_as_uint(f);
    return (u + 0x7fffu + ((u >> 16) & 1u)) >> 16;   // round-to-nearest-even
}
__device__ __forceinline__ unsigned int pack2(float a, float b) {
    return f2bf(a) | (f2bf(b) << 16);
}

// ---------------------------------------------------------------------------
// init: zero degree counters and BN stats accumulators
__global__ __launch_bounds__(256) void k_init(int* __restrict__ deg_cnt,
                                              float* __restrict__ stats, int n) {
    int i = blockIdx.x * 256 + threadIdx.x;
    if (i < n) deg_cnt[i] = 0;
    if (i < 512) stats[i] = 0.0f;
}

// in-degree histogram over dst
__global__ __launch_bounds__(256) void k_deg(const int* __restrict__ dst,
                                             int* __restrict__ deg_cnt, int e) {
    int i = blockIdx.x * 256 + threadIdx.x;
    if (i < e) atomicAdd(&deg_cnt[dst[i]], 1);
}

// dinv[i] = rsqrt(deg_cnt[i] + 1)   (self-loop adds 1)
__global__ __launch_bounds__(256) void k_dinv(const int* __restrict__ deg_cnt,
                                              float* __restrict__ dinv, int n) {
    int i = blockIdx.x * 256 + threadIdx.x;
    if (i < n) dinv[i] = rsqrtf((float)deg_cnt[i] + 1.0f);
}

// ---------------------------------------------------------------------------
// hierarchical exclusive scan (all 256-thread blocks)
__device__ __forceinline__ int wave_scan_incl(int v) {
    int lane = threadIdx.x & 63;
#pragma unroll
    for (int off = 1; off < 64; off <<= 1) {
        int t = __shfl_up(v, off, 64);
        if (lane >= off) v += t;
    }
    return v;
}

__global__ __launch_bounds__(256) void k_scan1(const int* __restrict__ deg_cnt,
                                               int* __restrict__ row_start,
                                               int* __restrict__ blk_sum, int n) {
    int tid = threadIdx.x;
    int i = blockIdx.x * 256 + tid;
    int v = (i < n) ? deg_cnt[i] : 0;
    int inc = wave_scan_incl(v);
    __shared__ int wtot[4];
    int wave = tid >> 6, lane = tid & 63;
    if (lane == 63) wtot[wave] = inc;
    __syncthreads();
    int woff = 0;
    for (int w = 0; w < wave; ++w) woff += wtot[w];
    int excl = woff + inc - v;
    if (i < n) row_start[i] = excl;
    if (tid == 255) blk_sum[blockIdx.x] = woff + inc;
}

__global__ __launch_bounds__(256) void k_scan2(const int* __restrict__ blk_sum,
                                               int* __restrict__ blk_off,
                                               int* __restrict__ row_start,
                                               int nblk, int n) {
    int tid = threadIdx.x;
    int v = (tid < nblk) ? blk_sum[tid] : 0;
    int inc = wave_scan_incl(v);
    __shared__ int wtot[4];
    int wave = tid >> 6, lane = tid & 63;
    if (lane == 63) wtot[wave] = inc;
    __syncthreads();
    int woff = 0;
    for (int w = 0; w < wave; ++w) woff += wtot[w];
    if (tid < nblk) blk_off[tid] = woff + inc - v;
    if (tid == 255) row_start[n] = woff + inc;   // grand total
}

__global__ __launch_bounds__(256) void k_scan3(int* __restrict__ row_start,
                                               const int* __restrict__ blk_off,
                                               int* __restrict__ cursor, int n) {
    int i = blockIdx.x * 256 + threadIdx.x;
    if (i < n) {
        int rs = row_start[i] + blk_off[blockIdx.x];
        row_start[i] = rs;
        cursor[i] = rs;
    }
}

// ---------------------------------------------------------------------------
// K-chunked GEMM body: H[r0b..r0b+31, :] = X[r0b..,:] @ W, bf16 output.
// 16-row W chunks (8 KB) + 32x16 X slice (2 KB) -> 10 KB LDS.
__device__ __forceinline__ void gemm_tile(const float* __restrict__ X,
                                          const float* __restrict__ W,
                                          unsigned short* __restrict__ H,
                                          int n, int r0b,
                                          float* __restrict__ ws,   // [16*DIM]
                                          float* __restrict__ xs) { // [32*16]
    int t = threadIdx.x;
    int ty = t >> 5;          // 0..7 -> 4-row group
    int tx = t & 31;          // 0..31 -> 4-col group
    int r0 = ty * 4;
    int c0 = tx * 4;
    float acc[4][4] = {};

    const float4* W4 = (const float4*)W;
    const float4* X4 = (const float4*)X;
    float4* ws4 = (float4*)ws;
    float4* xs4 = (float4*)xs;

    for (int c = 0; c < 8; ++c) {          // 8 chunks of K=16
        int k0 = c * 16;
        if (c) __syncthreads();            // protect LDS reuse
#pragma unroll
        for (int i = 0; i < 2; ++i) {
            int idx = t + 256 * i;         // 0..511 float4 of W chunk
            ws4[idx] = W4[k0 * 32 + idx];
        }
        if (t < 128) {
            int row = t >> 2;              // 0..31
            int cg  = t & 3;               // float4 within 16-col slice
            float4 v = make_float4(0.f, 0.f, 0.f, 0.f);
            if (r0b + row < n) v = X4[(size_t)(r0b + row) * 32 + (k0 >> 2) + cg];
            xs4[t] = v;
        }
        __syncthreads();
#pragma unroll
        for (int k = 0; k < 16; ++k) {
            float4 b = *(const float4*)&ws[k * DIM + c0];
            float a0 = xs[(r0 + 0) * 16 + k];
            float a1 = xs[(r0 + 1) * 16 + k];
            float a2 = xs[(r0 + 2) * 16 + k];
            float a3 = xs[(r0 + 3) * 16 + k];
            acc[0][0] += a0 * b.x; acc[0][1] += a0 * b.y; acc[0][2] += a0 * b.z; acc[0][3] += a0 * b.w;
            acc[1][0] += a1 * b.x; acc[1][1] += a1 * b.y; acc[1][2] += a1 * b.z; acc[1][3] += a1 * b.w;
            acc[2][0] += a2 * b.x; acc[2][1] += a2 * b.y; acc[2][2] += a2 * b.z; acc[2][3] += a2 * b.w;
            acc[3][0] += a3 * b.x; acc[3][1] += a3 * b.y; acc[3][2] += a3 * b.z; acc[3][3] += a3 * b.w;
        }
    }
#pragma unroll
    for (int i = 0; i < 4; ++i) {
        int row = r0b + r0 + i;
        if (row < n) {
            uint2 pv;
            pv.x = pack2(acc[i][0], acc[i][1]);
            pv.y = pack2(acc[i][2], acc[i][3]);
            *(uint2*)&H[(size_t)row * DIM + c0] = pv;   // 8B-aligned
        }
    }
}

// ---------------------------------------------------------------------------
// FUSED fill || GEMM1 with INTERLEAVED block mapping: block b is a GEMM block
// iff (b % 3 == 0 && b/3 < gemmBlocks); fill blocks take the remaining slots
// (fill_idx = b - #gemm-blocks-before-b). This keeps both types co-resident
// under (roughly in-order) dispatch so the GEMM's compute hides the scatter
// latency — R11/R12's tail layout ran the two phases serially instead.
__global__ __launch_bounds__(256) void k_fill_gemm(
        const int* __restrict__ src, const int* __restrict__ dst,
        const float* __restrict__ dinv, int* __restrict__ cursor,
        int2* __restrict__ edge, int e, int gemmBlocks,
        const float* __restrict__ X, const float* __restrict__ W,
        unsigned short* __restrict__ H, int n) {
    __shared__ float ws[16 * DIM];   // 8 KB
    __shared__ float xs[32 * 16];    // 2 KB

    int b = (int)blockIdx.x;
    int q = b / 3;
    bool isGemm = ((b % 3) == 0) && (q < gemmBlocks);
    if (!isGemm) {
        int nG = min(gemmBlocks, (b + 2) / 3);   // gemm blocks before b
        int i = (b - nG) * 256 + threadIdx.x;
        if (i < e) {
            int s = src[i], t = dst[i];
            int pos = atomicAdd(&cursor[t], 1);
            float w = dinv[s] * dinv[t];
            edge[pos] = make_int2(s, __float_as_int(w));
        }
        return;
    }
    gemm_tile(X, W, H, n, q * 32, ws, xs);
}

// H = X @ W   (standalone, used for conv2)
__global__ __launch_bounds__(256) void k_gemm(const float* __restrict__ X,
                                              const float* __restrict__ W,
                                              unsigned short* __restrict__ H, int n) {
    __shared__ float ws[16 * DIM];   // 8 KB
    __shared__ float xs[32 * 16];    // 2 KB
    gemm_tile(X, W, H, n, blockIdx.x * 32, ws, xs);
}

// ---------------------------------------------------------------------------
// out[i,:] = sum_{j in in-edges(i)} H[edge[j].x,:]*edge[j].w + H[i,:]*dinv[i]^2 + bias
// H is bf16. ONE WAVE per node (4 nodes / 256-thr block); lane owns channels
// 2*lane, 2*lane+1 via one packed uint load per edge; 8-edge unroll.
__global__ __launch_bounds__(256) void k_agg(const unsigned int* __restrict__ Hp,  // bf16 pairs
                                             const float* __restrict__ bias,
                                             const float* __restrict__ dinv,
                                             const int* __restrict__ row_start,
                                             const int2* __restrict__ edge,
                                             float* __restrict__ out, int n, int e) {
    int node = blockIdx.x * 4 + (threadIdx.x >> 6);
    int lane = threadIdx.x & 63;
    if (node >= n) return;
    float di = dinv[node];
    float dsq = di * di;
    float b0 = bias[2 * lane];
    float b1 = bias[2 * lane + 1];
    unsigned int hs = Hp[(size_t)node * 64 + lane];
    float a0 = bflo(hs) * dsq + b0;
    float a1 = bfhi(hs) * dsq + b1;
    int jb = row_start[node], je = row_start[node + 1];
    jb = min(max(jb, 0), e);          // clamp: garbage can't cause hang/OOB
    je = min(max(je, jb), e);
    int j = jb;
    for (; j + 8 <= je; j += 8) {
        int2 ed[8]; unsigned int h[8];
#pragma unroll
        for (int u = 0; u < 8; ++u) ed[u] = edge[j + u];
#pragma unroll
        for (int u = 0; u < 8; ++u) h[u] = Hp[(size_t)ed[u].x * 64 + lane];
#pragma unroll
        for (int u = 0; u < 8; ++u) {
            float w = __int_as_float(ed[u].y);
            a0 += bflo(h[u]) * w;
            a1 += bfhi(h[u]) * w;
        }
    }
    for (; j < je; ++j) {
        int2 ed = edge[j];
        float w = __int_as_float(ed.y);
        unsigned int h = Hp[(size_t)ed.x * 64 + lane];
        a0 += bflo(h) * w;
        a1 += bfhi(h) * w;
    }
    out[(size_t)node * DIM + 2 * lane]     = a0;
    out[(size_t)node * DIM + 2 * lane + 1] = a1;
}

// ---------------------------------------------------------------------------
// column sums + sums of squares -> sums[0..127]=sum, sums[128..255]=sumsq
__global__ __launch_bounds__(256) void k_stats(const float* __restrict__ V,
                                               float* __restrict__ sums, int n) {
    int d = threadIdx.x & 127;
    int half = threadIdx.x >> 7;
    int r0 = blockIdx.x * 256;
    int r1 = min(r0 + 256, n);
    float s = 0.f, q = 0.f;
    for (int r = r0 + half; r < r1; r += 2) {
        float v = V[(size_t)r * DIM + d];
        s += v; q += v * v;
    }
    __shared__ float ls[256], lq[256];
    ls[threadIdx.x] = s; lq[threadIdx.x] = q;
    __syncthreads();
    if (half == 0) {
        atomicAdd(&sums[d], s + ls[threadIdx.x + 128]);
        atomicAdd(&sums[128 + d], q + lq[threadIdx.x + 128]);
    }
}

// BN (training-mode batch stats) + ReLU, in place
__global__ __launch_bounds__(256) void k_bn_relu(float* __restrict__ V,
                                                 const float* __restrict__ sums,
                                                 const float* __restrict__ gamma,
                                                 const float* __restrict__ beta,
                                                 int n, float invN) {
    int idx = blockIdx.x * 256 + threadIdx.x;
    if (idx >= n * DIM) return;
    int d = idx & 127;
    float mu = sums[d] * invN;
    float var = sums[128 + d] * invN - mu * mu;
    float inv = rsqrtf(var + BN_EPS);
    float scale = gamma[d] * inv;
    float shift = beta[d] - mu * scale;
    float v = V[idx] * scale + shift;
    V[idx] = fmaxf(v, 0.f);
}

// BN + residual + ReLU -> out (element-wise; safe when V == out)
__global__ __launch_bounds__(256) void k_bn_res_relu(const float* __restrict__ V,
                                                     const float* __restrict__ X,
                                                     const float* __restrict__ sums,
                                                     const float* __restrict__ gamma,
                                                     const float* __restrict__ beta,
                                                     float* __restrict__ out,
                                                     int n, float invN) {
    int idx = blockIdx.x * 256 + threadIdx.x;
    if (idx >= n * DIM) return;
    int d = idx & 127;
    float mu = sums[d] * invN;
    float var = sums[128 + d] * invN - mu * mu;
    float inv = rsqrtf(var + BN_EPS);
    float scale = gamma[d] * inv;
    float shift = beta[d] - mu * scale;
    float v = V[idx] * scale + shift + X[idx];
    out[idx] = fmaxf(v, 0.f);
}

// ---------------------------------------------------------------------------
extern "C" void kernel_launch(void* const* d_in, const int* in_sizes, int n_in,
                              void* d_out, int out_size, void* d_ws, size_t ws_size,
                              hipStream_t stream) {
    const float* x      = (const float*)d_in[0];
    const int*   ei     = (const int*)d_in[1];
    const float* W1     = (const float*)d_in[2];
    const float* b1     = (const float*)d_in[3];
    const float* gamma1 = (const float*)d_in[4];
    const float* beta1  = (const float*)d_in[5];
    const float* W2     = (const float*)d_in[6];
    const float* b2     = (const float*)d_in[7];
    const float* gamma2 = (const float*)d_in[8];
    const float* beta2  = (const float*)d_in[9];
    float* out = (float*)d_out;

    int n = in_sizes[0] / DIM;   // 50000
    int e = in_sizes[1] / 2;     // 800000
    const int* srcIdx = ei;       // edge_index[0,:]
    const int* dstIdx = ei + e;   // edge_index[1,:]

    int gN    = (n + 255) / 256;
    int gE    = (e + 255) / 256;
    int gRows = (n + 31) / 32;
    int gNode = (n + 3) / 4;
    int gElem = (n * DIM + 255) / 256;
    float invN = 1.0f / (float)n;

    char* ws = (char*)d_ws;
    size_t off = 0;
    auto alloc = [&](size_t bytes) -> void* {
        void* p = ws + off;
        off += (bytes + 255) & ~(size_t)255;
        return p;
    };
    int*   deg_cnt   = (int*)  alloc((size_t)n * 4);
    float* dinv      = (float*)alloc((size_t)n * 4);
    int*   row_start = (int*)  alloc((size_t)(n + 1) * 4);
    int*   cursor    = (int*)  alloc((size_t)n * 4);
    int*   blk_sum   = (int*)  alloc((size_t)gN * 4);
    int*   blk_off   = (int*)  alloc((size_t)gN * 4);
    int2*  edge      = (int2*) alloc((size_t)e * 8);              // (src, wgt)
    unsigned short* Hb = (unsigned short*)alloc((size_t)n * DIM * 2);  // bf16 H
    float* stats     = (float*)alloc(512 * 4);   // [stats1 | stats2]
    float* stats1 = stats;
    float* stats2 = stats + 256;
    // d_out doubles as the fp32 N x D buffer (fully overwritten at the end,
    // final BN pass is element-wise in-place-safe).
    float* bufB = out;

    // workspace guard: fail cleanly (wrong output) instead of corrupting memory
    if (off > ws_size || gN > 256) return;

    // graph preprocessing: degrees -> dinv -> CSR prefix
    k_init<<<gN, 256, 0, stream>>>(deg_cnt, stats, n);
    k_deg<<<gE, 256, 0, stream>>>(dstIdx, deg_cnt, e);
    k_dinv<<<gN, 256, 0, stream>>>(deg_cnt, dinv, n);
    k_scan1<<<gN, 256, 0, stream>>>(deg_cnt, row_start, blk_sum, n);
    k_scan2<<<1, 256, 0, stream>>>(blk_sum, blk_off, row_start, gN, n);
    k_scan3<<<gN, 256, 0, stream>>>(row_start, blk_off, cursor, n);

    // FUSED: CSR fill (latency-bound) || GEMM1 (VALU-bound), interleaved 2:1
    k_fill_gemm<<<gE + gRows, 256, 0, stream>>>(
        srcIdx, dstIdx, dinv, cursor, edge, e, gRows,
        x, W1, Hb, n);

    // conv1 aggregation + BN + ReLU
    k_agg<<<gNode, 256, 0, stream>>>((const unsigned int*)Hb, b1, dinv, row_start, edge, bufB, n, e);
    k_stats<<<gN, 256, 0, stream>>>(bufB, stats1, n);
    k_bn_relu<<<gElem, 256, 0, stream>>>(bufB, stats1, gamma1, beta1, n, invN);

    // conv2 + BN + residual + ReLU
    k_gemm<<<gRows, 256, 0, stream>>>(bufB, W2, Hb, n);
    k_agg<<<gNode, 256, 0, stream>>>((const unsigned int*)Hb, b2, dinv, row_start, edge, bufB, n, e);
    k_stats<<<gN, 256, 0, stream>>>(bufB, stats2, n);
    k_bn_res_relu<<<gElem, 256, 0, stream>>>(bufB, x, stats2, gamma2, beta2, out, n, invN);
}

// Round 14
// 370.307 us; speedup vs baseline: 1.0981x; 1.0809x over previous
//
#include <hip/hip_runtime.h>

#define DIM 128
#define BN_EPS 1e-5f

// ---- bf16 helpers ----
__device__ __forceinline__ float bflo(unsigned int h) {
    return __uint_as_float(h << 16);
}
__device__ __forceinline__ float bfhi(unsigned int h) {
    return __uint_as_float(h & 0xffff0000u);
}
__device__ __forceinline__ unsigned int f2bf(float f) {
    unsigned int u = __float_as_uint(f);
    return (u + 0x7fffu + ((u >> 16) & 1u)) >> 16;   // round-to-nearest-even
}
__device__ __forceinline__ unsigned int pack2(float a, float b) {
    return f2bf(a) | (f2bf(b) << 16);
}

// ---------------------------------------------------------------------------
// init: zero degree counters and BN stats accumulators
__global__ __launch_bounds__(256) void k_init(int* __restrict__ deg_cnt,
                                              float* __restrict__ stats, int n) {
    int i = blockIdx.x * 256 + threadIdx.x;
    if (i < n) deg_cnt[i] = 0;
    if (i < 512) stats[i] = 0.0f;
}

// in-degree histogram over dst
__global__ __launch_bounds__(256) void k_deg(const int* __restrict__ dst,
                                             int* __restrict__ deg_cnt, int e) {
    int i = blockIdx.x * 256 + threadIdx.x;
    if (i < e) atomicAdd(&deg_cnt[dst[i]], 1);
}

// ---------------------------------------------------------------------------
// hierarchical exclusive scan (all 256-thread blocks)
__device__ __forceinline__ int wave_scan_incl(int v) {
    int lane = threadIdx.x & 63;
#pragma unroll
    for (int off = 1; off < 64; off <<= 1) {
        int t = __shfl_up(v, off, 64);
        if (lane >= off) v += t;
    }
    return v;
}

// stage 1: local exclusive scan -> row_start; block totals; also dinv
__global__ __launch_bounds__(256) void k_scan1(const int* __restrict__ deg_cnt,
                                               int* __restrict__ row_start,
                                               int* __restrict__ blk_sum,
                                               float* __restrict__ dinv, int n) {
    int tid = threadIdx.x;
    int i = blockIdx.x * 256 + tid;
    int v = (i < n) ? deg_cnt[i] : 0;
    if (i < n) dinv[i] = rsqrtf((float)v + 1.0f);   // fused: self-loop adds 1
    int inc = wave_scan_incl(v);
    __shared__ int wtot[4];
    int wave = tid >> 6, lane = tid & 63;
    if (lane == 63) wtot[wave] = inc;
    __syncthreads();
    int woff = 0;
    for (int w = 0; w < wave; ++w) woff += wtot[w];
    int excl = woff + inc - v;
    if (i < n) row_start[i] = excl;
    if (tid == 255) blk_sum[blockIdx.x] = woff + inc;
}

__global__ __launch_bounds__(256) void k_scan2(const int* __restrict__ blk_sum,
                                               int* __restrict__ blk_off,
                                               int* __restrict__ row_start,
                                               int nblk, int n) {
    int tid = threadIdx.x;
    int v = (tid < nblk) ? blk_sum[tid] : 0;
    int inc = wave_scan_incl(v);
    __shared__ int wtot[4];
    int wave = tid >> 6, lane = tid & 63;
    if (lane == 63) wtot[wave] = inc;
    __syncthreads();
    int woff = 0;
    for (int w = 0; w < wave; ++w) woff += wtot[w];
    if (tid < nblk) blk_off[tid] = woff + inc - v;
    if (tid == 255) row_start[n] = woff + inc;   // grand total
}

__global__ __launch_bounds__(256) void k_scan3(int* __restrict__ row_start,
                                               const int* __restrict__ blk_off,
                                               int* __restrict__ cursor, int n) {
    int i = blockIdx.x * 256 + threadIdx.x;
    if (i < n) {
        int rs = row_start[i] + blk_off[blockIdx.x];
        row_start[i] = rs;
        cursor[i] = rs;
    }
}

// ---------------------------------------------------------------------------
// per-channel BN(+ReLU) from raw column stats (training-mode, biased var)
__device__ __forceinline__ float bn_apply(float v, int c,
                                          const float* __restrict__ sums,
                                          const float* __restrict__ g,
                                          const float* __restrict__ b,
                                          float invN) {
    float mu = sums[c] * invN;
    float var = sums[128 + c] * invN - mu * mu;
    float inv = rsqrtf(var + BN_EPS);
    float sc = g[c] * inv;
    return fmaxf(v * sc + (b[c] - mu * sc), 0.f);
}

// K-chunked GEMM body: H[r0b..r0b+31, :] = BNReLU?(X[r0b..,:]) @ W, bf16 out.
// 16-row W chunks (8 KB) + 32x16 X slice (2 KB) -> 10 KB LDS.
__device__ __forceinline__ void gemm_tile(const float* __restrict__ X,
                                          const float* __restrict__ W,
                                          unsigned short* __restrict__ H,
                                          int n, int r0b,
                                          const float* __restrict__ sums,  // null -> raw X
                                          const float* __restrict__ gamma,
                                          const float* __restrict__ beta,
                                          float invN,
                                          float* __restrict__ ws,   // [16*DIM]
                                          float* __restrict__ xs) { // [32*16]
    int t = threadIdx.x;
    int ty = t >> 5;          // 0..7 -> 4-row group
    int tx = t & 31;          // 0..31 -> 4-col group
    int r0 = ty * 4;
    int c0 = tx * 4;
    float acc[4][4] = {};

    const float4* W4 = (const float4*)W;
    const float4* X4 = (const float4*)X;
    float4* ws4 = (float4*)ws;
    float4* xs4 = (float4*)xs;
    bool bn = (sums != nullptr);

    for (int c = 0; c < 8; ++c) {          // 8 chunks of K=16
        int k0 = c * 16;
        if (c) __syncthreads();            // protect LDS reuse
#pragma unroll
        for (int i = 0; i < 2; ++i) {
            int idx = t + 256 * i;         // 0..511 float4 of W chunk
            ws4[idx] = W4[k0 * 32 + idx];
        }
        if (t < 128) {
            int row = t >> 2;              // 0..31
            int cg  = t & 3;               // float4 within 16-col slice
            float4 v = make_float4(0.f, 0.f, 0.f, 0.f);
            if (r0b + row < n) {
                v = X4[(size_t)(r0b + row) * 32 + (k0 >> 2) + cg];
                if (bn) {
                    int ch = k0 + cg * 4;
                    v.x = bn_apply(v.x, ch + 0, sums, gamma, beta, invN);
                    v.y = bn_apply(v.y, ch + 1, sums, gamma, beta, invN);
                    v.z = bn_apply(v.z, ch + 2, sums, gamma, beta, invN);
                    v.w = bn_apply(v.w, ch + 3, sums, gamma, beta, invN);
                }
            }
            xs4[t] = v;
        }
        __syncthreads();
#pragma unroll
        for (int k = 0; k < 16; ++k) {
            float4 b = *(const float4*)&ws[k * DIM + c0];
            float a0 = xs[(r0 + 0) * 16 + k];
            float a1 = xs[(r0 + 1) * 16 + k];
            float a2 = xs[(r0 + 2) * 16 + k];
            float a3 = xs[(r0 + 3) * 16 + k];
            acc[0][0] += a0 * b.x; acc[0][1] += a0 * b.y; acc[0][2] += a0 * b.z; acc[0][3] += a0 * b.w;
            acc[1][0] += a1 * b.x; acc[1][1] += a1 * b.y; acc[1][2] += a1 * b.z; acc[1][3] += a1 * b.w;
            acc[2][0] += a2 * b.x; acc[2][1] += a2 * b.y; acc[2][2] += a2 * b.z; acc[2][3] += a2 * b.w;
            acc[3][0] += a3 * b.x; acc[3][1] += a3 * b.y; acc[3][2] += a3 * b.z; acc[3][3] += a3 * b.w;
        }
    }
#pragma unroll
    for (int i = 0; i < 4; ++i) {
        int row = r0b + r0 + i;
        if (row < n) {
            uint2 pv;
            pv.x = pack2(acc[i][0], acc[i][1]);
            pv.y = pack2(acc[i][2], acc[i][3]);
            *(uint2*)&H[(size_t)row * DIM + c0] = pv;   // 8B-aligned
        }
    }
}

// ---------------------------------------------------------------------------
// FUSED fill || GEMM1 with interleaved block mapping (gemm iff b%3==0 && b/3
// < gemmBlocks) — keeps both types co-resident so GEMM compute hides the
// scatter latency.
__global__ __launch_bounds__(256) void k_fill_gemm(
        const int* __restrict__ src, const int* __restrict__ dst,
        const float* __restrict__ dinv, int* __restrict__ cursor,
        int2* __restrict__ edge, int e, int gemmBlocks,
        const float* __restrict__ X, const float* __restrict__ W,
        unsigned short* __restrict__ H, int n) {
    __shared__ float ws[16 * DIM];   // 8 KB
    __shared__ float xs[32 * 16];    // 2 KB

    int b = (int)blockIdx.x;
    int q = b / 3;
    bool isGemm = ((b % 3) == 0) && (q < gemmBlocks);
    if (!isGemm) {
        int nG = min(gemmBlocks, (b + 2) / 3);   // gemm blocks before b
        int i = (b - nG) * 256 + threadIdx.x;
        if (i < e) {
            int s = src[i], t = dst[i];
            int pos = atomicAdd(&cursor[t], 1);
            float w = dinv[s] * dinv[t];
            edge[pos] = make_int2(s, __float_as_int(w));
        }
        return;
    }
    gemm_tile(X, W, H, n, q * 32, nullptr, nullptr, nullptr, 0.f, ws, xs);
}

// H = BNReLU?(X) @ W   (standalone; BN fused for conv2)
__global__ __launch_bounds__(256) void k_gemm(const float* __restrict__ X,
                                              const float* __restrict__ W,
                                              const float* __restrict__ sums,
                                              const float* __restrict__ gamma,
                                              const float* __restrict__ beta,
                                              unsigned short* __restrict__ H,
                                              int n, float invN) {
    __shared__ float ws[16 * DIM];   // 8 KB
    __shared__ float xs[32 * 16];    // 2 KB
    gemm_tile(X, W, H, n, blockIdx.x * 32, sums, gamma, beta, invN, ws, xs);
}

// ---------------------------------------------------------------------------
// out[i,:] = sum_{j in in-edges(i)} H[edge[j].x,:]*edge[j].w + H[i,:]*dinv[i]^2 + bias
// H is bf16. ONE WAVE per node (4 nodes / 256-thr block); lane owns channels
// 2*lane, 2*lane+1 via one packed uint load per edge; 8-edge unroll.
__global__ __launch_bounds__(256) void k_agg(const unsigned int* __restrict__ Hp,  // bf16 pairs
                                             const float* __restrict__ bias,
                                             const float* __restrict__ dinv,
                                             const int* __restrict__ row_start,
                                             const int2* __restrict__ edge,
                                             float* __restrict__ out, int n, int e) {
    int node = blockIdx.x * 4 + (threadIdx.x >> 6);
    int lane = threadIdx.x & 63;
    if (node >= n) return;
    float di = dinv[node];
    float dsq = di * di;
    float b0 = bias[2 * lane];
    float b1 = bias[2 * lane + 1];
    unsigned int hs = Hp[(size_t)node * 64 + lane];
    float a0 = bflo(hs) * dsq + b0;
    float a1 = bfhi(hs) * dsq + b1;
    int jb = row_start[node], je = row_start[node + 1];
    jb = min(max(jb, 0), e);          // clamp: garbage can't cause hang/OOB
    je = min(max(je, jb), e);
    int j = jb;
    for (; j + 8 <= je; j += 8) {
        int2 ed[8]; unsigned int h[8];
#pragma unroll
        for (int u = 0; u < 8; ++u) ed[u] = edge[j + u];
#pragma unroll
        for (int u = 0; u < 8; ++u) h[u] = Hp[(size_t)ed[u].x * 64 + lane];
#pragma unroll
        for (int u = 0; u < 8; ++u) {
            float w = __int_as_float(ed[u].y);
            a0 += bflo(h[u]) * w;
            a1 += bfhi(h[u]) * w;
        }
    }
    for (; j < je; ++j) {
        int2 ed = edge[j];
        float w = __int_as_float(ed.y);
        unsigned int h = Hp[(size_t)ed.x * 64 + lane];
        a0 += bflo(h) * w;
        a1 += bfhi(h) * w;
    }
    out[(size_t)node * DIM + 2 * lane]     = a0;
    out[(size_t)node * DIM + 2 * lane + 1] = a1;
}

// ---------------------------------------------------------------------------
// column sums + sums of squares; 64 rows/block for latency hiding
__global__ __launch_bounds__(256) void k_stats(const float* __restrict__ V,
                                               float* __restrict__ sums, int n) {
    int d = threadIdx.x & 127;
    int half = threadIdx.x >> 7;
    int r0 = blockIdx.x * 64;
    int r1 = min(r0 + 64, n);
    float s = 0.f, q = 0.f;
    for (int r = r0 + half; r < r1; r += 2) {
        float v = V[(size_t)r * DIM + d];
        s += v; q += v * v;
    }
    __shared__ float ls[256], lq[256];
    ls[threadIdx.x] = s; lq[threadIdx.x] = q;
    __syncthreads();
    if (half == 0) {
        atomicAdd(&sums[d], s + ls[threadIdx.x + 128]);
        atomicAdd(&sums[128 + d], q + lq[threadIdx.x + 128]);
    }
}

// BN + residual + ReLU -> out (element-wise; safe when V == out)
__global__ __launch_bounds__(256) void k_bn_res_relu(const float* __restrict__ V,
                                                     const float* __restrict__ X,
                                                     const float* __restrict__ sums,
                                                     const float* __restrict__ gamma,
                                                     const float* __restrict__ beta,
                                                     float* __restrict__ out,
                                                     int n, float invN) {
    int idx = blockIdx.x * 256 + threadIdx.x;
    if (idx >= n * DIM) return;
    int d = idx & 127;
    float mu = sums[d] * invN;
    float var = sums[128 + d] * invN - mu * mu;
    float inv = rsqrtf(var + BN_EPS);
    float scale = gamma[d] * inv;
    float shift = beta[d] - mu * scale;
    float v = V[idx] * scale + shift + X[idx];
    out[idx] = fmaxf(v, 0.f);
}

// ---------------------------------------------------------------------------
extern "C" void kernel_launch(void* const* d_in, const int* in_sizes, int n_in,
                              void* d_out, int out_size, void* d_ws, size_t ws_size,
                              hipStream_t stream) {
    const float* x      = (const float*)d_in[0];
    const int*   ei     = (const int*)d_in[1];
    const float* W1     = (const float*)d_in[2];
    const float* b1     = (const float*)d_in[3];
    const float* gamma1 = (const float*)d_in[4];
    const float* beta1  = (const float*)d_in[5];
    const float* W2     = (const float*)d_in[6];
    const float* b2     = (const float*)d_in[7];
    const float* gamma2 = (const float*)d_in[8];
    const float* beta2  = (const float*)d_in[9];
    float* out = (float*)d_out;

    int n = in_sizes[0] / DIM;   // 50000
    int e = in_sizes[1] / 2;     // 800000
    const int* srcIdx = ei;       // edge_index[0,:]
    const int* dstIdx = ei + e;   // edge_index[1,:]

    int gN    = (n + 255) / 256;
    int gE    = (e + 255) / 256;
    int gRows = (n + 31) / 32;
    int gNode = (n + 3) / 4;
    int gS    = (n + 63) / 64;
    int gElem = (n * DIM + 255) / 256;
    float invN = 1.0f / (float)n;

    char* ws = (char*)d_ws;
    size_t off = 0;
    auto alloc = [&](size_t bytes) -> void* {
        void* p = ws + off;
        off += (bytes + 255) & ~(size_t)255;
        return p;
    };
    int*   deg_cnt   = (int*)  alloc((size_t)n * 4);
    float* dinv      = (float*)alloc((size_t)n * 4);
    int*   row_start = (int*)  alloc((size_t)(n + 1) * 4);
    int*   cursor    = (int*)  alloc((size_t)n * 4);
    int*   blk_sum   = (int*)  alloc((size_t)gN * 4);
    int*   blk_off   = (int*)  alloc((size_t)gN * 4);
    int2*  edge      = (int2*) alloc((size_t)e * 8);              // (src, wgt)
    unsigned short* Hb = (unsigned short*)alloc((size_t)n * DIM * 2);  // bf16 H
    float* stats     = (float*)alloc(512 * 4);   // [stats1 | stats2]
    float* stats1 = stats;
    float* stats2 = stats + 256;
    // d_out doubles as the fp32 N x D buffer (fully overwritten at the end,
    // final BN pass is element-wise in-place-safe).
    float* bufB = out;

    // workspace guard: fail cleanly (wrong output) instead of corrupting memory
    if (off > ws_size || gN > 256) return;

    // graph preprocessing: degrees -> (dinv + scan) -> CSR prefix
    k_init<<<gN, 256, 0, stream>>>(deg_cnt, stats, n);
    k_deg<<<gE, 256, 0, stream>>>(dstIdx, deg_cnt, e);
    k_scan1<<<gN, 256, 0, stream>>>(deg_cnt, row_start, blk_sum, dinv, n);
    k_scan2<<<1, 256, 0, stream>>>(blk_sum, blk_off, row_start, gN, n);
    k_scan3<<<gN, 256, 0, stream>>>(row_start, blk_off, cursor, n);

    // FUSED: CSR fill (latency-bound) || GEMM1 (VALU-bound), interleaved
    k_fill_gemm<<<gE + gRows, 256, 0, stream>>>(
        srcIdx, dstIdx, dinv, cursor, edge, e, gRows,
        x, W1, Hb, n);

    // conv1 aggregation + stats
    k_agg<<<gNode, 256, 0, stream>>>((const unsigned int*)Hb, b1, dinv, row_start, edge, bufB, n, e);
    k_stats<<<gS, 256, 0, stream>>>(bufB, stats1, n);

    // conv2 (BN1+ReLU fused into X staging) + stats + final BN+res+ReLU
    k_gemm<<<gRows, 256, 0, stream>>>(bufB, W2, stats1, gamma1, beta1, Hb, n, invN);
    k_agg<<<gNode, 256, 0, stream>>>((const unsigned int*)Hb, b2, dinv, row_start, edge, bufB, n, e);
    k_stats<<<gS, 256, 0, stream>>>(bufB, stats2, n);
    k_bn_res_relu<<<gElem, 256, 0, stream>>>(bufB, x, stats2, gamma2, beta2, out, n, invN);
}

// Round 15
// 362.496 us; speedup vs baseline: 1.1218x; 1.0215x over previous
//
#include <hip/hip_runtime.h>

#define DIM 128
#define BN_EPS 1e-5f

// ---- bf16 helpers ----
__device__ __forceinline__ float bflo(unsigned int h) {
    return __uint_as_float(h << 16);
}
__device__ __forceinline__ float bfhi(unsigned int h) {
    return __uint_as_float(h & 0xffff0000u);
}
__device__ __forceinline__ unsigned int f2bf(float f) {
    unsigned int u = __float_as_uint(f);
    return (u + 0x7fffu + ((u >> 16) & 1u)) >> 16;   // round-to-nearest-even
}
__device__ __forceinline__ unsigned int pack2(float a, float b) {
    return f2bf(a) | (f2bf(b) << 16);
}

// ---------------------------------------------------------------------------
// init: zero degree counters and BN stats accumulators
__global__ __launch_bounds__(256) void k_init(int* __restrict__ deg_cnt,
                                              float* __restrict__ stats, int n) {
    int i = blockIdx.x * 256 + threadIdx.x;
    if (i < n) deg_cnt[i] = 0;
    if (i < 512) stats[i] = 0.0f;
}

// in-degree histogram over dst; 4 edges/thread for 4 outstanding atomic chains
__global__ __launch_bounds__(256) void k_deg(const int* __restrict__ dst,
                                             int* __restrict__ deg_cnt, int e) {
    int base = blockIdx.x * 1024 + threadIdx.x;
    int i0 = base, i1 = base + 256, i2 = base + 512, i3 = base + 768;
    int d0 = (i0 < e) ? dst[i0] : -1;
    int d1 = (i1 < e) ? dst[i1] : -1;
    int d2 = (i2 < e) ? dst[i2] : -1;
    int d3 = (i3 < e) ? dst[i3] : -1;
    if (d0 >= 0) atomicAdd(&deg_cnt[d0], 1);
    if (d1 >= 0) atomicAdd(&deg_cnt[d1], 1);
    if (d2 >= 0) atomicAdd(&deg_cnt[d2], 1);
    if (d3 >= 0) atomicAdd(&deg_cnt[d3], 1);
}

// ---------------------------------------------------------------------------
// hierarchical exclusive scan (all 256-thread blocks)
__device__ __forceinline__ int wave_scan_incl(int v) {
    int lane = threadIdx.x & 63;
#pragma unroll
    for (int off = 1; off < 64; off <<= 1) {
        int t = __shfl_up(v, off, 64);
        if (lane >= off) v += t;
    }
    return v;
}

// stage 1: local exclusive scan -> row_start; block totals; also dinv
__global__ __launch_bounds__(256) void k_scan1(const int* __restrict__ deg_cnt,
                                               int* __restrict__ row_start,
                                               int* __restrict__ blk_sum,
                                               float* __restrict__ dinv, int n) {
    int tid = threadIdx.x;
    int i = blockIdx.x * 256 + tid;
    int v = (i < n) ? deg_cnt[i] : 0;
    if (i < n) dinv[i] = rsqrtf((float)v + 1.0f);   // fused: self-loop adds 1
    int inc = wave_scan_incl(v);
    __shared__ int wtot[4];
    int wave = tid >> 6, lane = tid & 63;
    if (lane == 63) wtot[wave] = inc;
    __syncthreads();
    int woff = 0;
    for (int w = 0; w < wave; ++w) woff += wtot[w];
    int excl = woff + inc - v;
    if (i < n) row_start[i] = excl;
    if (tid == 255) blk_sum[blockIdx.x] = woff + inc;
}

__global__ __launch_bounds__(256) void k_scan2(const int* __restrict__ blk_sum,
                                               int* __restrict__ blk_off,
                                               int* __restrict__ row_start,
                                               int nblk, int n) {
    int tid = threadIdx.x;
    int v = (tid < nblk) ? blk_sum[tid] : 0;
    int inc = wave_scan_incl(v);
    __shared__ int wtot[4];
    int wave = tid >> 6, lane = tid & 63;
    if (lane == 63) wtot[wave] = inc;
    __syncthreads();
    int woff = 0;
    for (int w = 0; w < wave; ++w) woff += wtot[w];
    if (tid < nblk) blk_off[tid] = woff + inc - v;
    if (tid == 255) row_start[n] = woff + inc;   // grand total
}

__global__ __launch_bounds__(256) void k_scan3(int* __restrict__ row_start,
                                               const int* __restrict__ blk_off,
                                               int* __restrict__ cursor, int n) {
    int i = blockIdx.x * 256 + threadIdx.x;
    if (i < n) {
        int rs = row_start[i] + blk_off[blockIdx.x];
        row_start[i] = rs;
        cursor[i] = rs;
    }
}

// ---------------------------------------------------------------------------
// per-channel BN(+ReLU) from raw column stats (training-mode, biased var)
__device__ __forceinline__ float bn_apply(float v, int c,
                                          const float* __restrict__ sums,
                                          const float* __restrict__ g,
                                          const float* __restrict__ b,
                                          float invN) {
    float mu = sums[c] * invN;
    float var = sums[128 + c] * invN - mu * mu;
    float inv = rsqrtf(var + BN_EPS);
    float sc = g[c] * inv;
    return fmaxf(v * sc + (b[c] - mu * sc), 0.f);
}

// K-chunked GEMM body: H[r0b..r0b+31, :] = BNReLU?(X[r0b..,:]) @ W, bf16 out.
// 16-row W chunks (8 KB) + 32x16 X slice (2 KB) -> 10 KB LDS.
__device__ __forceinline__ void gemm_tile(const float* __restrict__ X,
                                          const float* __restrict__ W,
                                          unsigned short* __restrict__ H,
                                          int n, int r0b,
                                          const float* __restrict__ sums,  // null -> raw X
                                          const float* __restrict__ gamma,
                                          const float* __restrict__ beta,
                                          float invN,
                                          float* __restrict__ ws,   // [16*DIM]
                                          float* __restrict__ xs) { // [32*16]
    int t = threadIdx.x;
    int ty = t >> 5;          // 0..7 -> 4-row group
    int tx = t & 31;          // 0..31 -> 4-col group
    int r0 = ty * 4;
    int c0 = tx * 4;
    float acc[4][4] = {};

    const float4* W4 = (const float4*)W;
    const float4* X4 = (const float4*)X;
    float4* ws4 = (float4*)ws;
    float4* xs4 = (float4*)xs;
    bool bn = (sums != nullptr);

    for (int c = 0; c < 8; ++c) {          // 8 chunks of K=16
        int k0 = c * 16;
        if (c) __syncthreads();            // protect LDS reuse
#pragma unroll
        for (int i = 0; i < 2; ++i) {
            int idx = t + 256 * i;         // 0..511 float4 of W chunk
            ws4[idx] = W4[k0 * 32 + idx];
        }
        if (t < 128) {
            int row = t >> 2;              // 0..31
            int cg  = t & 3;               // float4 within 16-col slice
            float4 v = make_float4(0.f, 0.f, 0.f, 0.f);
            if (r0b + row < n) {
                v = X4[(size_t)(r0b + row) * 32 + (k0 >> 2) + cg];
                if (bn) {
                    int ch = k0 + cg * 4;
                    v.x = bn_apply(v.x, ch + 0, sums, gamma, beta, invN);
                    v.y = bn_apply(v.y, ch + 1, sums, gamma, beta, invN);
                    v.z = bn_apply(v.z, ch + 2, sums, gamma, beta, invN);
                    v.w = bn_apply(v.w, ch + 3, sums, gamma, beta, invN);
                }
            }
            xs4[t] = v;
        }
        __syncthreads();
#pragma unroll
        for (int k = 0; k < 16; ++k) {
            float4 b = *(const float4*)&ws[k * DIM + c0];
            float a0 = xs[(r0 + 0) * 16 + k];
            float a1 = xs[(r0 + 1) * 16 + k];
            float a2 = xs[(r0 + 2) * 16 + k];
            float a3 = xs[(r0 + 3) * 16 + k];
            acc[0][0] += a0 * b.x; acc[0][1] += a0 * b.y; acc[0][2] += a0 * b.z; acc[0][3] += a0 * b.w;
            acc[1][0] += a1 * b.x; acc[1][1] += a1 * b.y; acc[1][2] += a1 * b.z; acc[1][3] += a1 * b.w;
            acc[2][0] += a2 * b.x; acc[2][1] += a2 * b.y; acc[2][2] += a2 * b.z; acc[2][3] += a2 * b.w;
            acc[3][0] += a3 * b.x; acc[3][1] += a3 * b.y; acc[3][2] += a3 * b.z; acc[3][3] += a3 * b.w;
        }
    }
#pragma unroll
    for (int i = 0; i < 4; ++i) {
        int row = r0b + r0 + i;
        if (row < n) {
            uint2 pv;
            pv.x = pack2(acc[i][0], acc[i][1]);
            pv.y = pack2(acc[i][2], acc[i][3]);
            *(uint2*)&H[(size_t)row * DIM + c0] = pv;   // 8B-aligned
        }
    }
}

// ---------------------------------------------------------------------------
// FUSED fill || GEMM1, 1:1 interleave: even blocks (while they last) run the
// GEMM, odd blocks run the fill with 2 edges/thread (512 edges/block) — both
// types co-resident, 2 outstanding scatter chains per fill thread.
__global__ __launch_bounds__(256) void k_fill_gemm(
        const int* __restrict__ src, const int* __restrict__ dst,
        const float* __restrict__ dinv, int* __restrict__ cursor,
        int2* __restrict__ edge, int e, int gemmBlocks,
        const float* __restrict__ X, const float* __restrict__ W,
        unsigned short* __restrict__ H, int n) {
    __shared__ float ws[16 * DIM];   // 8 KB
    __shared__ float xs[32 * 16];    // 2 KB

    int b = (int)blockIdx.x;
    bool isGemm = ((b & 1) == 0) && ((b >> 1) < gemmBlocks);
    if (!isGemm) {
        int nG = min(gemmBlocks, (b + 1) >> 1);   // gemm blocks before b
        int base = (b - nG) * 512 + threadIdx.x;
        int i0 = base, i1 = base + 256;
        bool v0 = i0 < e, v1 = i1 < e;
        int s0 = v0 ? src[i0] : 0, t0 = v0 ? dst[i0] : 0;
        int s1 = v1 ? src[i1] : 0, t1 = v1 ? dst[i1] : 0;
        float w0 = v0 ? dinv[s0] * dinv[t0] : 0.f;
        float w1 = v1 ? dinv[s1] * dinv[t1] : 0.f;
        if (v0) {
            int pos = atomicAdd(&cursor[t0], 1);
            edge[pos] = make_int2(s0, __float_as_int(w0));
        }
        if (v1) {
            int pos = atomicAdd(&cursor[t1], 1);
            edge[pos] = make_int2(s1, __float_as_int(w1));
        }
        return;
    }
    gemm_tile(X, W, H, n, (b >> 1) * 32, nullptr, nullptr, nullptr, 0.f, ws, xs);
}

// H = BNReLU?(X) @ W   (standalone; BN fused for conv2)
__global__ __launch_bounds__(256) void k_gemm(const float* __restrict__ X,
                                              const float* __restrict__ W,
                                              const float* __restrict__ sums,
                                              const float* __restrict__ gamma,
                                              const float* __restrict__ beta,
                                              unsigned short* __restrict__ H,
                                              int n, float invN) {
    __shared__ float ws[16 * DIM];   // 8 KB
    __shared__ float xs[32 * 16];    // 2 KB
    gemm_tile(X, W, H, n, blockIdx.x * 32, sums, gamma, beta, invN, ws, xs);
}

// ---------------------------------------------------------------------------
// out[i,:] = sum_{j in in-edges(i)} H[edge[j].x,:]*edge[j].w + H[i,:]*dinv[i]^2 + bias
// H is bf16. ONE WAVE per node; lane owns channels 2*lane, 2*lane+1 via one
// packed uint load per edge; 16-edge main unroll + 4-step mid + scalar tail.
__global__ __launch_bounds__(256) void k_agg(const unsigned int* __restrict__ Hp,  // bf16 pairs
                                             const float* __restrict__ bias,
                                             const float* __restrict__ dinv,
                                             const int* __restrict__ row_start,
                                             const int2* __restrict__ edge,
                                             float* __restrict__ out, int n, int e) {
    int node = blockIdx.x * 4 + (threadIdx.x >> 6);
    int lane = threadIdx.x & 63;
    if (node >= n) return;
    float di = dinv[node];
    float dsq = di * di;
    float b0 = bias[2 * lane];
    float b1 = bias[2 * lane + 1];
    unsigned int hs = Hp[(size_t)node * 64 + lane];
    float a0 = bflo(hs) * dsq + b0;
    float a1 = bfhi(hs) * dsq + b1;
    int jb = row_start[node], je = row_start[node + 1];
    jb = min(max(jb, 0), e);          // clamp: garbage can't cause hang/OOB
    je = min(max(je, jb), e);
    int j = jb;
    for (; j + 16 <= je; j += 16) {
        int2 ed[16]; unsigned int h[16];
#pragma unroll
        for (int u = 0; u < 16; ++u) ed[u] = edge[j + u];
#pragma unroll
        for (int u = 0; u < 16; ++u) h[u] = Hp[(size_t)ed[u].x * 64 + lane];
#pragma unroll
        for (int u = 0; u < 16; ++u) {
            float w = __int_as_float(ed[u].y);
            a0 += bflo(h[u]) * w;
            a1 += bfhi(h[u]) * w;
        }
    }
    for (; j + 4 <= je; j += 4) {
        int2 ed[4]; unsigned int h[4];
#pragma unroll
        for (int u = 0; u < 4; ++u) ed[u] = edge[j + u];
#pragma unroll
        for (int u = 0; u < 4; ++u) h[u] = Hp[(size_t)ed[u].x * 64 + lane];
#pragma unroll
        for (int u = 0; u < 4; ++u) {
            float w = __int_as_float(ed[u].y);
            a0 += bflo(h[u]) * w;
            a1 += bfhi(h[u]) * w;
        }
    }
    for (; j < je; ++j) {
        int2 ed = edge[j];
        float w = __int_as_float(ed.y);
        unsigned int h = Hp[(size_t)ed.x * 64 + lane];
        a0 += bflo(h) * w;
        a1 += bfhi(h) * w;
    }
    out[(size_t)node * DIM + 2 * lane]     = a0;
    out[(size_t)node * DIM + 2 * lane + 1] = a1;
}

// ---------------------------------------------------------------------------
// column sums + sums of squares; 64 rows/block for latency hiding
__global__ __launch_bounds__(256) void k_stats(const float* __restrict__ V,
                                               float* __restrict__ sums, int n) {
    int d = threadIdx.x & 127;
    int half = threadIdx.x >> 7;
    int r0 = blockIdx.x * 64;
    int r1 = min(r0 + 64, n);
    float s = 0.f, q = 0.f;
    for (int r = r0 + half; r < r1; r += 2) {
        float v = V[(size_t)r * DIM + d];
        s += v; q += v * v;
    }
    __shared__ float ls[256], lq[256];
    ls[threadIdx.x] = s; lq[threadIdx.x] = q;
    __syncthreads();
    if (half == 0) {
        atomicAdd(&sums[d], s + ls[threadIdx.x + 128]);
        atomicAdd(&sums[128 + d], q + lq[threadIdx.x + 128]);
    }
}

// BN + residual + ReLU -> out (element-wise; safe when V == out)
__global__ __launch_bounds__(256) void k_bn_res_relu(const float* __restrict__ V,
                                                     const float* __restrict__ X,
                                                     const float* __restrict__ sums,
                                                     const float* __restrict__ gamma,
                                                     const float* __restrict__ beta,
                                                     float* __restrict__ out,
                                                     int n, float invN) {
    int idx = blockIdx.x * 256 + threadIdx.x;
    if (idx >= n * DIM) return;
    int d = idx & 127;
    float mu = sums[d] * invN;
    float var = sums[128 + d] * invN - mu * mu;
    float inv = rsqrtf(var + BN_EPS);
    float scale = gamma[d] * inv;
    float shift = beta[d] - mu * scale;
    float v = V[idx] * scale + shift + X[idx];
    out[idx] = fmaxf(v, 0.f);
}

// ---------------------------------------------------------------------------
extern "C" void kernel_launch(void* const* d_in, const int* in_sizes, int n_in,
                              void* d_out, int out_size, void* d_ws, size_t ws_size,
                              hipStream_t stream) {
    const float* x      = (const float*)d_in[0];
    const int*   ei     = (const int*)d_in[1];
    const float* W1     = (const float*)d_in[2];
    const float* b1     = (const float*)d_in[3];
    const float* gamma1 = (const float*)d_in[4];
    const float* beta1  = (const float*)d_in[5];
    const float* W2     = (const float*)d_in[6];
    const float* b2     = (const float*)d_in[7];
    const float* gamma2 = (const float*)d_in[8];
    const float* beta2  = (const float*)d_in[9];
    float* out = (float*)d_out;

    int n = in_sizes[0] / DIM;   // 50000
    int e = in_sizes[1] / 2;     // 800000
    const int* srcIdx = ei;       // edge_index[0,:]
    const int* dstIdx = ei + e;   // edge_index[1,:]

    int gN    = (n + 255) / 256;
    int gE4   = (e + 1023) / 1024;
    int gF2   = (e + 511) / 512;   // fill blocks at 2 edges/thread
    int gRows = (n + 31) / 32;
    int gNode = (n + 3) / 4;
    int gS    = (n + 63) / 64;
    int gElem = (n * DIM + 255) / 256;
    float invN = 1.0f / (float)n;

    char* ws = (char*)d_ws;
    size_t off = 0;
    auto alloc = [&](size_t bytes) -> void* {
        void* p = ws + off;
        off += (bytes + 255) & ~(size_t)255;
        return p;
    };
    int*   deg_cnt   = (int*)  alloc((size_t)n * 4);
    float* dinv      = (float*)alloc((size_t)n * 4);
    int*   row_start = (int*)  alloc((size_t)(n + 1) * 4);
    int*   cursor    = (int*)  alloc((size_t)n * 4);
    int*   blk_sum   = (int*)  alloc((size_t)gN * 4);
    int*   blk_off   = (int*)  alloc((size_t)gN * 4);
    int2*  edge      = (int2*) alloc((size_t)e * 8);              // (src, wgt)
    unsigned short* Hb = (unsigned short*)alloc((size_t)n * DIM * 2);  // bf16 H
    float* stats     = (float*)alloc(512 * 4);   // [stats1 | stats2]
    float* stats1 = stats;
    float* stats2 = stats + 256;
    // d_out doubles as the fp32 N x D buffer (fully overwritten at the end,
    // final BN pass is element-wise in-place-safe).
    float* bufB = out;

    // workspace guard: fail cleanly (wrong output) instead of corrupting memory
    if (off > ws_size || gN > 256) return;

    // graph preprocessing: degrees -> (dinv + scan) -> CSR prefix
    k_init<<<gN, 256, 0, stream>>>(deg_cnt, stats, n);
    k_deg<<<gE4, 256, 0, stream>>>(dstIdx, deg_cnt, e);
    k_scan1<<<gN, 256, 0, stream>>>(deg_cnt, row_start, blk_sum, dinv, n);
    k_scan2<<<1, 256, 0, stream>>>(blk_sum, blk_off, row_start, gN, n);
    k_scan3<<<gN, 256, 0, stream>>>(row_start, blk_off, cursor, n);

    // FUSED: CSR fill (2 edges/thr, latency-bound) || GEMM1, 1:1 interleave
    k_fill_gemm<<<gF2 + gRows, 256, 0, stream>>>(
        srcIdx, dstIdx, dinv, cursor, edge, e, gRows,
        x, W1, Hb, n);

    // conv1 aggregation + stats
    k_agg<<<gNode, 256, 0, stream>>>((const unsigned int*)Hb, b1, dinv, row_start, edge, bufB, n, e);
    k_stats<<<gS, 256, 0, stream>>>(bufB, stats1, n);

    // conv2 (BN1+ReLU fused into X staging) + stats + final BN+res+ReLU
    k_gemm<<<gRows, 256, 0, stream>>>(bufB, W2, stats1, gamma1, beta1, Hb, n, invN);
    k_agg<<<gNode, 256, 0, stream>>>((const unsigned int*)Hb, b2, dinv, row_start, edge, bufB, n, e);
    k_stats<<<gS, 256, 0, stream>>>(bufB, stats2, n);
    k_bn_res_relu<<<gElem, 256, 0, stream>>>(bufB, x, stats2, gamma2, beta2, out, n, invN);
}